// Round 3
// baseline (2667.280 us; speedup 1.0000x reference)
//
#include <hip/hip_runtime.h>

#define BATCH 64
#define SEQ   2048
#define HID   256

typedef _Float16 f16;
typedef __attribute__((ext_vector_type(8))) _Float16 f16x8;
typedef __attribute__((ext_vector_type(4))) float f32x4;
typedef __attribute__((ext_vector_type(4))) int i32x4;

// s_waitcnt immediates (gfx9 encoding: vm[3:0]|exp[6:4]|lgkm[11:8]|vm_hi[15:14])
#define WAITCNT_LGKM0_ONLY 0xC07F   // lgkmcnt(0), vmcnt=63, expcnt=7
#define WAITCNT_VM12       0x0F7C   // vmcnt(12), lgkmcnt=15, expcnt=7

__device__ __forceinline__ float fast_sigmoid(float z) {
    return __builtin_amdgcn_rcpf(1.0f + __builtin_amdgcn_exp2f(-1.4426950408889634f * z));
}
__device__ __forceinline__ float fast_tanh(float z) {
    return 2.0f * __builtin_amdgcn_rcpf(1.0f + __builtin_amdgcn_exp2f(-2.8853900817779268f * z)) - 1.0f;
}

#if __has_builtin(__builtin_amdgcn_sdot4)
__device__ __forceinline__ int dot4(int a, int b, int c) {
    return __builtin_amdgcn_sdot4(a, b, c, false);
}
#else
__device__ __forceinline__ int dot4(int a, int b, int c) {
#pragma unroll
    for (int i = 0; i < 4; ++i) {
        int ab = (a << (24 - 8 * i)) >> 24;
        int bb = (b << (24 - 8 * i)) >> 24;
        c += ab * bb;
    }
    return c;
}
#endif

// async global->LDS, 16B per lane; LDS dest = uniform base + lane*16
typedef __attribute__((address_space(3))) unsigned int lds_u32;
typedef __attribute__((address_space(1))) const unsigned int gbl_u32;
__device__ __forceinline__ void gload16(void* l, const void* g) {
    __builtin_amdgcn_global_load_lds((gbl_u32*)g, (lds_u32*)l, 16, 0, 0);
}

// ---------------------------------------------------------------------------
// Phase 1: xU[m,0:1024] = x[m,0:256] @ [U_i|U_f|U_o|U_c] + bias -> fp16.
// (unchanged — verified)
// ---------------------------------------------------------------------------
__global__ __launch_bounds__(256, 2) void xu_gemm(
    const float* __restrict__ x,
    const float* __restrict__ U0, const float* __restrict__ U1,
    const float* __restrict__ U2, const float* __restrict__ U3,
    const float* __restrict__ b0, const float* __restrict__ b1,
    const float* __restrict__ b2, const float* __restrict__ b3,
    f16* __restrict__ xU)
{
    __shared__ f16 As[128][40];   // A[m][k], stride 80B (16B-aligned rows)
    __shared__ f16 Bs[128][40];   // B^T: Bs[n][k]

    const int m0 = blockIdx.x * 128;
    const int n0 = blockIdx.y * 128;
    const int gate = n0 >> 8;          // 128-col block lies within one gate
    const int nc0 = n0 & 255;
    const float* U    = (gate == 0) ? U0 : (gate == 1) ? U1 : (gate == 2) ? U2 : U3;
    const float* bias = (gate == 0) ? b0 : (gate == 1) ? b1 : (gate == 2) ? b2 : b3;

    const int tid  = threadIdx.x;
    const int wv   = tid >> 6;
    const int lane = tid & 63;
    const int arow = tid >> 1, acq = (tid & 1) * 16;   // A staging: 2 thr/row
    const int brow = tid >> 3, bcq = (tid & 7) * 16;   // B staging: 8 thr/k-row

    f32x4 acc[2][8];
#pragma unroll
    for (int mt = 0; mt < 2; ++mt)
#pragma unroll
        for (int nt = 0; nt < 8; ++nt) acc[mt][nt] = (f32x4){0.f, 0.f, 0.f, 0.f};

    for (int kc = 0; kc < 8; ++kc) {
        const int k0 = kc * 32;
        // stage A tile [128 x 32] fp32 -> fp16
        {
            const float* src = x + (size_t)(m0 + arow) * 256 + k0 + acq;
            float4 v0 = *(const float4*)src;
            float4 v1 = *(const float4*)(src + 4);
            float4 v2 = *(const float4*)(src + 8);
            float4 v3 = *(const float4*)(src + 12);
            f16x8 h0, h1;
            h0[0] = (f16)v0.x; h0[1] = (f16)v0.y; h0[2] = (f16)v0.z; h0[3] = (f16)v0.w;
            h0[4] = (f16)v1.x; h0[5] = (f16)v1.y; h0[6] = (f16)v1.z; h0[7] = (f16)v1.w;
            h1[0] = (f16)v2.x; h1[1] = (f16)v2.y; h1[2] = (f16)v2.z; h1[3] = (f16)v2.w;
            h1[4] = (f16)v3.x; h1[5] = (f16)v3.y; h1[6] = (f16)v3.z; h1[7] = (f16)v3.w;
            *(f16x8*)&As[arow][acq] = h0;
            *(f16x8*)&As[arow][acq + 8] = h1;
        }
        // stage B tile [32 x 128] transposed into Bs[n][k]
        {
            const float* src = U + (size_t)(k0 + brow) * 256 + nc0 + bcq;
            float4 v0 = *(const float4*)src;
            float4 v1 = *(const float4*)(src + 4);
            float4 v2 = *(const float4*)(src + 8);
            float4 v3 = *(const float4*)(src + 12);
            Bs[bcq +  0][brow] = (f16)v0.x;  Bs[bcq +  1][brow] = (f16)v0.y;
            Bs[bcq +  2][brow] = (f16)v0.z;  Bs[bcq +  3][brow] = (f16)v0.w;
            Bs[bcq +  4][brow] = (f16)v1.x;  Bs[bcq +  5][brow] = (f16)v1.y;
            Bs[bcq +  6][brow] = (f16)v1.z;  Bs[bcq +  7][brow] = (f16)v1.w;
            Bs[bcq +  8][brow] = (f16)v2.x;  Bs[bcq +  9][brow] = (f16)v2.y;
            Bs[bcq + 10][brow] = (f16)v2.z;  Bs[bcq + 11][brow] = (f16)v2.w;
            Bs[bcq + 12][brow] = (f16)v3.x;  Bs[bcq + 13][brow] = (f16)v3.y;
            Bs[bcq + 14][brow] = (f16)v3.z;  Bs[bcq + 15][brow] = (f16)v3.w;
        }
        __syncthreads();
        const int qk = (lane >> 4) * 8;
        f16x8 afrag0 = *(const f16x8*)&As[wv * 32 +  0 + (lane & 15)][qk];
        f16x8 afrag1 = *(const f16x8*)&As[wv * 32 + 16 + (lane & 15)][qk];
#pragma unroll
        for (int nt = 0; nt < 8; ++nt) {
            f16x8 bfrag = *(const f16x8*)&Bs[nt * 16 + (lane & 15)][qk];
            acc[0][nt] = __builtin_amdgcn_mfma_f32_16x16x32_f16(afrag0, bfrag, acc[0][nt], 0, 0, 0);
            acc[1][nt] = __builtin_amdgcn_mfma_f32_16x16x32_f16(afrag1, bfrag, acc[1][nt], 0, 0, 0);
        }
        __syncthreads();
    }
    // C/D: col = lane&15 (n), row = (lane>>4)*4 + reg (m)
    const int col = lane & 15, quad = lane >> 4;
#pragma unroll
    for (int nt = 0; nt < 8; ++nt) {
        const int n = n0 + nt * 16 + col;
        const float bv = bias[n & 255];
#pragma unroll
        for (int mt = 0; mt < 2; ++mt) {
#pragma unroll
            for (int r = 0; r < 4; ++r) {
                const int m = m0 + wv * 32 + mt * 16 + quad * 4 + r;
                xU[(size_t)m * 1024 + n] = (f16)(acc[mt][nt][r] + bv);
            }
        }
    }
}

// ---------------------------------------------------------------------------
// Phase 2: recurrence. 64 blocks x 512 threads (8 waves, 2/SIMD).
// Round-3: HYBRID pipe split. Round-2 counters: MFMA busy ~48%, VALU ~36%
// on active CUs, and they SERIALIZE (ACT depends on own MFMAs). So split
// each wave's 32 columns across both pipes:
//   tile A (j = wv*32 + c):      MFMA path, 16 MFMAs/wave (was 32)
//   tile B (j = wv*32 + 16 + c): VALU v_dot4 path, 4-way K-split across
//       q-groups; REUSES the exact a0..a3 h-fragments loaded for MFMA
//       (lane q's dot K-set == its MFMA A-slices); 2 exact shfl_xor adds
//       combine the 4 partials.
// The wave issues its MFMAs first, then runs dot4s on the VALU while the
// matrix pipe drains -> the two ~600-1000 cy phases overlap instead of
// summing. Quantization identical -> integer sums bit-identical to r2.
// ---------------------------------------------------------------------------
__global__ __launch_bounds__(512, 2) void lstm_rec(
    const f16* __restrict__ xU,
    const float* __restrict__ V0, const float* __restrict__ V1,
    const float* __restrict__ V2, const float* __restrict__ V3,
    float* __restrict__ out)
{
    const int b    = blockIdx.x;
    const int tid  = threadIdx.x;
    const int wv   = tid >> 6;        // wave 0..7 -> cols [wv*32, wv*32+32)
    const int lane = tid & 63;
    const int q    = lane >> 4;       // k-group (MFMA A-slice / dot K-quarter)
    const int c    = lane & 15;       // column within 16-group
    const int hf   = q >> 1;          // this thread's column half
    const int j    = wv * 32 + hf * 16 + c;   // this thread's hidden index
    const int jw   = !(lane & 16);    // writer lane for j (q==0 or q==2)

    // Weight packing (identical quantization to verified rounds):
    //   word (g,kc,u) byte bb = V_g[kc*64 + q*16 + u*4 + bb][jn], scale 2048.
    // bregA: jn = wv*32 + c      (tile A, MFMA B-fragments)
    // wdot:  jn = wv*32 + 16 + c (tile B, VALU dot4 weights)
    i32x4 bregA[4][4];
    i32x4 wdot[4][4];
#pragma unroll
    for (int g = 0; g < 4; ++g) {
        const float* vp = (g == 0) ? V0 : (g == 1) ? V1 : (g == 2) ? V2 : V3;
        const int jA = wv * 32 + c;
        const int jB = wv * 32 + 16 + c;
#pragma unroll
        for (int kc = 0; kc < 4; ++kc) {
#pragma unroll
            for (int u = 0; u < 4; ++u) {
                int pA = 0, pB = 0;
#pragma unroll
                for (int bb = 0; bb < 4; ++bb) {
                    const int k = kc * 64 + q * 16 + u * 4 + bb;
                    float vA = vp[(size_t)k * 256 + jA];
                    float vB = vp[(size_t)k * 256 + jB];
                    int qA = __float2int_rn(vA * 2048.0f);
                    int qB = __float2int_rn(vB * 2048.0f);
                    qA = qA > 127 ? 127 : (qA < -127 ? -127 : qA);
                    qB = qB > 127 ? 127 : (qB < -127 ? -127 : qB);
                    pA |= (qA & 0xFF) << (8 * bb);
                    pB |= (qB & 0xFF) << (8 * bb);
                }
                bregA[g][kc][u] = pA;
                wdot[g][kc][u]  = pB;
            }
        }
    }

    __shared__ alignas(16) int hq[2][64];          // packed int8 h, dbuf
    __shared__ alignas(16) f16 xq[8][1024];        // xU ring, 2KB/slot
    if (tid < 64) { hq[0][tid] = 0; hq[1][tid] = 0; }

    const f16* xrow = xU + (size_t)b * SEQ * 1024;
    float* hrow = out + (size_t)b * SEQ * HID;

    // prefill ring slots 0..6 (wave 0 issues; __syncthreads drains vmcnt)
    if (wv == 0) {
#pragma unroll
        for (int s = 0; s < 7; ++s) {
            const f16* src = xrow + (size_t)s * 1024 + lane * 8;
            gload16(&xq[s][0], src);
            gload16(&xq[s][512], src + 512);
        }
    }
    float cs = 0.0f, hl = 0.0f;
    __syncthreads();

    const float INVS = 1.0f / (127.0f * 2048.0f);

    for (int t = 0; t < SEQ; ++t) {
        const int cur = t & 1, nxt = cur ^ 1;
        // issue next ring slot (7 steps ahead); vmcnt(12) proves slot t+1 done
        if (wv == 0) {
            const int tf = (t + 7 < SEQ) ? (t + 7) : (SEQ - 1);
            const int sl7 = (t + 7) & 7;
            const f16* src = xrow + (size_t)tf * 1024 + lane * 8;
            gload16(&xq[sl7][0], src);
            gload16(&xq[sl7][512], src + 512);
            __builtin_amdgcn_s_waitcnt(WAITCNT_VM12);
        }

        // xU additive terms for this thread's j (independent of h)
        const int sl = t & 7;
        const float xz0 = (float)xq[sl][      j];
        const float xz1 = (float)xq[sl][256 + j];
        const float xz2 = (float)xq[sl][512 + j];
        const float xz3 = (float)xq[sl][768 + j];

        // h fragments (shared by BOTH paths): lane q's K-slices, 4 b128
        // broadcast reads. a_kc covers k in [kc*64 + q*16, kc*64 + q*16 + 16).
        const int4* hp = (const int4*)&hq[cur][0];
        int4 h0 = hp[q];
        int4 h1 = hp[4 + q];
        int4 h2 = hp[8 + q];
        int4 h3 = hp[12 + q];
        const i32x4 a0 = (i32x4){h0.x, h0.y, h0.z, h0.w};
        const i32x4 a1 = (i32x4){h1.x, h1.y, h1.z, h1.w};
        const i32x4 a2 = (i32x4){h2.x, h2.y, h2.z, h2.w};
        const i32x4 a3 = (i32x4){h3.x, h3.y, h3.z, h3.w};

        // --- tile A: 16 MFMAs (matrix pipe; results consumed late) ---
        i32x4 dA[4], dB[4];
#pragma unroll
        for (int g = 0; g < 4; ++g) {
            dA[g] = __builtin_amdgcn_mfma_i32_16x16x64_i8(a0, bregA[g][0], (i32x4){0,0,0,0}, 0, 0, 0);
            dB[g] = __builtin_amdgcn_mfma_i32_16x16x64_i8(a2, bregA[g][2], (i32x4){0,0,0,0}, 0, 0, 0);
        }
#pragma unroll
        for (int g = 0; g < 4; ++g) {
            dA[g] = __builtin_amdgcn_mfma_i32_16x16x64_i8(a1, bregA[g][1], dA[g], 0, 0, 0);
            dB[g] = __builtin_amdgcn_mfma_i32_16x16x64_i8(a3, bregA[g][3], dB[g], 0, 0, 0);
        }

        // --- tile B: dot4 on VALU while the matrix pipe drains ---
        // per gate: two independent 8-dot chains, then exact int add
        int ad[4];
#pragma unroll
        for (int g = 0; g < 4; ++g) {
            int p0 = 0, p1 = 0;
            p0 = dot4(a0[0], wdot[g][0][0], p0); p0 = dot4(a0[1], wdot[g][0][1], p0);
            p0 = dot4(a0[2], wdot[g][0][2], p0); p0 = dot4(a0[3], wdot[g][0][3], p0);
            p1 = dot4(a1[0], wdot[g][1][0], p1); p1 = dot4(a1[1], wdot[g][1][1], p1);
            p1 = dot4(a1[2], wdot[g][1][2], p1); p1 = dot4(a1[3], wdot[g][1][3], p1);
            p0 = dot4(a2[0], wdot[g][2][0], p0); p0 = dot4(a2[1], wdot[g][2][1], p0);
            p0 = dot4(a2[2], wdot[g][2][2], p0); p0 = dot4(a2[3], wdot[g][2][3], p0);
            p1 = dot4(a3[0], wdot[g][3][0], p1); p1 = dot4(a3[1], wdot[g][3][1], p1);
            p1 = dot4(a3[2], wdot[g][3][2], p1); p1 = dot4(a3[3], wdot[g][3][3], p1);
            ad[g] = p0 + p1;
        }
        // butterfly-combine the 4 K-quarters (exact int adds)
#pragma unroll
        for (int g = 0; g < 4; ++g) {
            ad[g] += __shfl_xor(ad[g], 16, 64);
            ad[g] += __shfl_xor(ad[g], 32, 64);
        }

        // per-lane select: hf0 lanes take MFMA sums, hf1 lanes take dot sums
        const int si = (q & 2) ? ad[0] : (dA[0][0] + dB[0][0]);
        const int sf = (q & 2) ? ad[1] : (dA[1][0] + dB[1][0]);
        const int so = (q & 2) ? ad[2] : (dA[2][0] + dB[2][0]);
        const int sc = (q & 2) ? ad[3] : (dA[3][0] + dB[3][0]);

        const float zi = xz0 + (float)si * INVS;
        const float zf = xz1 + (float)sf * INVS;
        const float zo = xz2 + (float)so * INVS;
        const float zc = xz3 + (float)sc * INVS;
        const float ig = fast_sigmoid(zi);
        const float fg = fast_sigmoid(zf);
        const float og = fast_sigmoid(zo);
        const float gg = fast_tanh(zc);
        cs = fg * cs + ig * gg;
        const float hv = og * fast_tanh(cs);
        hl = hv;
        if (jw) {
            ((char*)&hq[nxt][0])[j] = (char)__float2int_rn(hv * 127.0f);
            hrow[t * HID + j] = hv;                 // fire-and-forget store
        }
        // barrier: drain LDS ops only (no vmcnt(0) HBM round-trip)
        __builtin_amdgcn_s_waitcnt(WAITCNT_LGKM0_ONLY);
        __builtin_amdgcn_s_barrier();
    }
    if (jw) {
        out[(size_t)BATCH * SEQ * HID + (size_t)b * HID + j] = hl;
        out[(size_t)BATCH * SEQ * HID + (size_t)BATCH * HID + (size_t)b * HID + j] = cs;
    }
}

extern "C" void kernel_launch(void* const* d_in, const int* in_sizes, int n_in,
                              void* d_out, int out_size, void* d_ws, size_t ws_size,
                              hipStream_t stream) {
    const float* x  = (const float*)d_in[0];
    const float* Ui = (const float*)d_in[1];
    const float* Vi = (const float*)d_in[2];
    const float* bi = (const float*)d_in[3];
    const float* Uf = (const float*)d_in[4];
    const float* Vf = (const float*)d_in[5];
    const float* bf = (const float*)d_in[6];
    const float* Uo = (const float*)d_in[7];
    const float* Vo = (const float*)d_in[8];
    const float* bo = (const float*)d_in[9];
    const float* Uc = (const float*)d_in[10];
    const float* Vc = (const float*)d_in[11];
    const float* bc = (const float*)d_in[12];

    f16* xU = (f16*)d_ws;   // [131072, 1024] fp16 = 256 MiB

    dim3 g1(1024, 8);   // (M/128, 4H/128)
    xu_gemm<<<g1, 256, 0, stream>>>(x, Ui, Uf, Uo, Uc, bi, bf, bo, bc, xU);
    lstm_rec<<<64, 512, 0, stream>>>(xU, Vi, Vf, Vo, Vc, (float*)d_out);
}

// Round 5
// 2139.090 us; speedup vs baseline: 1.2469x; 1.2469x over previous
//
#include <hip/hip_runtime.h>

#define BATCH 64
#define SEQ   2048
#define HID   256

typedef _Float16 f16;
typedef __attribute__((ext_vector_type(8))) _Float16 f16x8;
typedef __attribute__((ext_vector_type(4))) float f32x4;
typedef __attribute__((ext_vector_type(4))) int i32x4;

// s_waitcnt immediates (gfx9 encoding: vm[3:0]|exp[6:4]|lgkm[11:8]|vm_hi[15:14])
#define WAITCNT_LGKM0_ONLY 0xC07F   // lgkmcnt(0), vmcnt=63, expcnt=7
#define WAITCNT_VM12       0x0F7C   // vmcnt(12), lgkmcnt=15, expcnt=7

__device__ __forceinline__ float fast_sigmoid(float z) {
    return __builtin_amdgcn_rcpf(1.0f + __builtin_amdgcn_exp2f(-1.4426950408889634f * z));
}
__device__ __forceinline__ float fast_tanh(float z) {
    return 2.0f * __builtin_amdgcn_rcpf(1.0f + __builtin_amdgcn_exp2f(-2.8853900817779268f * z)) - 1.0f;
}

// async global->LDS, 16B per lane; LDS dest = uniform base + lane*16
typedef __attribute__((address_space(3))) unsigned int lds_u32;
typedef __attribute__((address_space(1))) const unsigned int gbl_u32;
__device__ __forceinline__ void gload16(void* l, const void* g) {
    __builtin_amdgcn_global_load_lds((gbl_u32*)g, (lds_u32*)l, 16, 0, 0);
}

// ---------------------------------------------------------------------------
// Phase 1: xU[m,0:1024] = x[m,0:256] @ [U_i|U_f|U_o|U_c] + bias -> fp16.
// (unchanged — verified)
// ---------------------------------------------------------------------------
__global__ __launch_bounds__(256, 2) void xu_gemm(
    const float* __restrict__ x,
    const float* __restrict__ U0, const float* __restrict__ U1,
    const float* __restrict__ U2, const float* __restrict__ U3,
    const float* __restrict__ b0, const float* __restrict__ b1,
    const float* __restrict__ b2, const float* __restrict__ b3,
    f16* __restrict__ xU)
{
    __shared__ f16 As[128][40];   // A[m][k], stride 80B (16B-aligned rows)
    __shared__ f16 Bs[128][40];   // B^T: Bs[n][k]

    const int m0 = blockIdx.x * 128;
    const int n0 = blockIdx.y * 128;
    const int gate = n0 >> 8;          // 128-col block lies within one gate
    const int nc0 = n0 & 255;
    const float* U    = (gate == 0) ? U0 : (gate == 1) ? U1 : (gate == 2) ? U2 : U3;
    const float* bias = (gate == 0) ? b0 : (gate == 1) ? b1 : (gate == 2) ? b2 : b3;

    const int tid  = threadIdx.x;
    const int wv   = tid >> 6;
    const int lane = tid & 63;
    const int arow = tid >> 1, acq = (tid & 1) * 16;   // A staging: 2 thr/row
    const int brow = tid >> 3, bcq = (tid & 7) * 16;   // B staging: 8 thr/k-row

    f32x4 acc[2][8];
#pragma unroll
    for (int mt = 0; mt < 2; ++mt)
#pragma unroll
        for (int nt = 0; nt < 8; ++nt) acc[mt][nt] = (f32x4){0.f, 0.f, 0.f, 0.f};

    for (int kc = 0; kc < 8; ++kc) {
        const int k0 = kc * 32;
        // stage A tile [128 x 32] fp32 -> fp16
        {
            const float* src = x + (size_t)(m0 + arow) * 256 + k0 + acq;
            float4 v0 = *(const float4*)src;
            float4 v1 = *(const float4*)(src + 4);
            float4 v2 = *(const float4*)(src + 8);
            float4 v3 = *(const float4*)(src + 12);
            f16x8 h0, h1;
            h0[0] = (f16)v0.x; h0[1] = (f16)v0.y; h0[2] = (f16)v0.z; h0[3] = (f16)v0.w;
            h0[4] = (f16)v1.x; h0[5] = (f16)v1.y; h0[6] = (f16)v1.z; h0[7] = (f16)v1.w;
            h1[0] = (f16)v2.x; h1[1] = (f16)v2.y; h1[2] = (f16)v2.z; h1[3] = (f16)v2.w;
            h1[4] = (f16)v3.x; h1[5] = (f16)v3.y; h1[6] = (f16)v3.z; h1[7] = (f16)v3.w;
            *(f16x8*)&As[arow][acq] = h0;
            *(f16x8*)&As[arow][acq + 8] = h1;
        }
        // stage B tile [32 x 128] transposed into Bs[n][k]
        {
            const float* src = U + (size_t)(k0 + brow) * 256 + nc0 + bcq;
            float4 v0 = *(const float4*)src;
            float4 v1 = *(const float4*)(src + 4);
            float4 v2 = *(const float4*)(src + 8);
            float4 v3 = *(const float4*)(src + 12);
            Bs[bcq +  0][brow] = (f16)v0.x;  Bs[bcq +  1][brow] = (f16)v0.y;
            Bs[bcq +  2][brow] = (f16)v0.z;  Bs[bcq +  3][brow] = (f16)v0.w;
            Bs[bcq +  4][brow] = (f16)v1.x;  Bs[bcq +  5][brow] = (f16)v1.y;
            Bs[bcq +  6][brow] = (f16)v1.z;  Bs[bcq +  7][brow] = (f16)v1.w;
            Bs[bcq +  8][brow] = (f16)v2.x;  Bs[bcq +  9][brow] = (f16)v2.y;
            Bs[bcq + 10][brow] = (f16)v2.z;  Bs[bcq + 11][brow] = (f16)v2.w;
            Bs[bcq + 12][brow] = (f16)v3.x;  Bs[bcq + 13][brow] = (f16)v3.y;
            Bs[bcq + 14][brow] = (f16)v3.z;  Bs[bcq + 15][brow] = (f16)v3.w;
        }
        __syncthreads();
        const int qk = (lane >> 4) * 8;
        f16x8 afrag0 = *(const f16x8*)&As[wv * 32 +  0 + (lane & 15)][qk];
        f16x8 afrag1 = *(const f16x8*)&As[wv * 32 + 16 + (lane & 15)][qk];
#pragma unroll
        for (int nt = 0; nt < 8; ++nt) {
            f16x8 bfrag = *(const f16x8*)&Bs[nt * 16 + (lane & 15)][qk];
            acc[0][nt] = __builtin_amdgcn_mfma_f32_16x16x32_f16(afrag0, bfrag, acc[0][nt], 0, 0, 0);
            acc[1][nt] = __builtin_amdgcn_mfma_f32_16x16x32_f16(afrag1, bfrag, acc[1][nt], 0, 0, 0);
        }
        __syncthreads();
    }
    // C/D: col = lane&15 (n), row = (lane>>4)*4 + reg (m)
    const int col = lane & 15, quad = lane >> 4;
#pragma unroll
    for (int nt = 0; nt < 8; ++nt) {
        const int n = n0 + nt * 16 + col;
        const float bv = bias[n & 255];
#pragma unroll
        for (int mt = 0; mt < 2; ++mt) {
#pragma unroll
            for (int r = 0; r < 4; ++r) {
                const int m = m0 + wv * 32 + mt * 16 + quad * 4 + r;
                xU[(size_t)m * 1024 + n] = (f16)(acc[mt][nt][r] + bv);
            }
        }
    }
}

// ---------------------------------------------------------------------------
// Phase 2: recurrence. 64 blocks x 512 threads (8 waves, 2/SIMD).
// Round-5 = round-4 schedule with the GATE-INDEX BUG fixed:
//   breg[g] is packed from V0..V3 = (i, f, o, c), so the o-gate sum is
//   acc[2] and the c-gate sum is acc[3] (as in verified rounds 1-3).
//   Round 4 had them swapped -> absmax 0.36. Now: sc <- acc[3], so <- acc[2].
// Schedule (unchanged from r4): 8 depth-4 MFMA chains issued round-robin,
// all 32 in flight before any D-read; xz reads after MFMA issue; per-gate
// ACT so early chains' activation overlaps late chains' drain.
// ---------------------------------------------------------------------------
__global__ __launch_bounds__(512, 2) void lstm_rec(
    const f16* __restrict__ xU,
    const float* __restrict__ V0, const float* __restrict__ V1,
    const float* __restrict__ V2, const float* __restrict__ V3,
    float* __restrict__ out)
{
    const int b    = blockIdx.x;
    const int tid  = threadIdx.x;
    const int wv   = tid >> 6;        // wave 0..7 -> cols [wv*32, wv*32+32)
    const int lane = tid & 63;
    const int q    = lane >> 4;       // MFMA k-group
    const int c    = lane & 15;       // MFMA column within 16-group
    const int hf   = q >> 1;          // this thread's column half
    const int j    = wv * 32 + hf * 16 + c;   // this thread's hidden index
    const int jw   = !(lane & 16);    // writer lane for j (q==0 or q==2)

    // quantize V columns into B fragments: breg[g][hfi][kc] holds
    // V_g[kc*64 + q*16 + u*4 + bb][wv*32 + hfi*16 + c] as int8, byte bb of word u
    // gate order g = 0:i, 1:f, 2:o, 3:c  (V2 = V_o, V3 = V_c!)
    i32x4 breg[4][2][4];
#pragma unroll
    for (int g = 0; g < 4; ++g) {
        const float* vp = (g == 0) ? V0 : (g == 1) ? V1 : (g == 2) ? V2 : V3;
#pragma unroll
        for (int hfi = 0; hfi < 2; ++hfi) {
            const int jn = wv * 32 + hfi * 16 + c;
#pragma unroll
            for (int kc = 0; kc < 4; ++kc) {
#pragma unroll
                for (int u = 0; u < 4; ++u) {
                    int packed = 0;
#pragma unroll
                    for (int bb = 0; bb < 4; ++bb) {
                        const int k = kc * 64 + q * 16 + u * 4 + bb;
                        float v = vp[(size_t)k * 256 + jn];
                        int qv = __float2int_rn(v * 2048.0f);
                        qv = qv > 127 ? 127 : (qv < -127 ? -127 : qv);
                        packed |= (qv & 0xFF) << (8 * bb);
                    }
                    breg[g][hfi][kc][u] = packed;
                }
            }
        }
    }

    __shared__ alignas(16) int hq[2][64];          // packed int8 h, dbuf
    __shared__ alignas(16) f16 xq[8][1024];        // xU ring, 2KB/slot
    if (tid < 64) { hq[0][tid] = 0; hq[1][tid] = 0; }

    const f16* xrow = xU + (size_t)b * SEQ * 1024;
    float* hrow = out + (size_t)b * SEQ * HID;

    // prefill ring slots 0..6 (wave 0 issues; __syncthreads drains vmcnt)
    if (wv == 0) {
#pragma unroll
        for (int s = 0; s < 7; ++s) {
            const f16* src = xrow + (size_t)s * 1024 + lane * 8;
            gload16(&xq[s][0], src);
            gload16(&xq[s][512], src + 512);
        }
    }
    float cs = 0.0f, hl = 0.0f;
    __syncthreads();

    const float INVS = 1.0f / (127.0f * 2048.0f);

    for (int t = 0; t < SEQ; ++t) {
        const int cur = t & 1, nxt = cur ^ 1;
        // issue next ring slot (7 steps ahead); vmcnt(12) proves slot t+1 done
        if (wv == 0) {
            const int tf = (t + 7 < SEQ) ? (t + 7) : (SEQ - 1);
            const int sl7 = (t + 7) & 7;
            const f16* src = xrow + (size_t)tf * 1024 + lane * 8;
            gload16(&xq[sl7][0], src);
            gload16(&xq[sl7][512], src + 512);
            __builtin_amdgcn_s_waitcnt(WAITCNT_VM12);
        }

        // A fragments: broadcast b128 reads of packed-int8 h (4 K-chunks).
        const int4* hp = (const int4*)&hq[cur][0];
        int4 h0 = hp[q];       // kc 0: h bytes [q*16 .. q*16+15]
        int4 h1 = hp[4 + q];   // kc 1
        int4 h2 = hp[8 + q];   // kc 2
        int4 h3 = hp[12 + q];  // kc 3
        const i32x4 a0 = (i32x4){h0.x, h0.y, h0.z, h0.w};
        const i32x4 a1 = (i32x4){h1.x, h1.y, h1.z, h1.w};
        const i32x4 a2 = (i32x4){h2.x, h2.y, h2.z, h2.w};
        const i32x4 a3 = (i32x4){h3.x, h3.y, h3.z, h3.w};

        // --- MFMA phase: 8 depth-4 chains, round-robin issue, no D reads.
        // All 32 issued before any consumption -> matrix pipe fills.
        i32x4 acc[4][2];
#pragma unroll
        for (int g = 0; g < 4; ++g)
#pragma unroll
            for (int hfi = 0; hfi < 2; ++hfi)
                acc[g][hfi] = __builtin_amdgcn_mfma_i32_16x16x64_i8(a0, breg[g][hfi][0], (i32x4){0,0,0,0}, 0, 0, 0);
#pragma unroll
        for (int g = 0; g < 4; ++g)
#pragma unroll
            for (int hfi = 0; hfi < 2; ++hfi)
                acc[g][hfi] = __builtin_amdgcn_mfma_i32_16x16x64_i8(a1, breg[g][hfi][1], acc[g][hfi], 0, 0, 0);
#pragma unroll
        for (int g = 0; g < 4; ++g)
#pragma unroll
            for (int hfi = 0; hfi < 2; ++hfi)
                acc[g][hfi] = __builtin_amdgcn_mfma_i32_16x16x64_i8(a2, breg[g][hfi][2], acc[g][hfi], 0, 0, 0);
#pragma unroll
        for (int g = 0; g < 4; ++g)
#pragma unroll
            for (int hfi = 0; hfi < 2; ++hfi)
                acc[g][hfi] = __builtin_amdgcn_mfma_i32_16x16x64_i8(a3, breg[g][hfi][3], acc[g][hfi], 0, 0, 0);

        // xU additive terms (issued after MFMAs; LDS latency hides in drain)
        const int sl = t & 7;
        const float xz0 = (float)xq[sl][      j];
        const float xz1 = (float)xq[sl][256 + j];
        const float xz2 = (float)xq[sl][512 + j];
        const float xz3 = (float)xq[sl][768 + j];

        // --- ACT, per gate (gate index: acc[0]=i, acc[1]=f, acc[2]=o, acc[3]=c) ---
        // gate i
        const int  si = (q & 2) ? acc[0][1][0] : acc[0][0][0];
        const float zi = xz0 + (float)si * INVS;
        const float ig = fast_sigmoid(zi);
        // gate f
        const int  sf = (q & 2) ? acc[1][1][0] : acc[1][0][0];
        const float zf = xz1 + (float)sf * INVS;
        const float fg = fast_sigmoid(zf);
        // gate c (cell candidate) -> cs chain
        const int  sc = (q & 2) ? acc[3][1][0] : acc[3][0][0];
        const float zc = xz3 + (float)sc * INVS;
        const float gg = fast_tanh(zc);
        cs = fg * cs + ig * gg;
        // gate o
        const int  so = (q & 2) ? acc[2][1][0] : acc[2][0][0];
        const float zo = xz2 + (float)so * INVS;
        const float og = fast_sigmoid(zo);
        const float hv = og * fast_tanh(cs);
        hl = hv;
        if (jw) {
            ((char*)&hq[nxt][0])[j] = (char)__float2int_rn(hv * 127.0f);
            hrow[t * HID + j] = hv;                 // fire-and-forget store
        }
        // barrier: drain LDS ops only (no vmcnt(0) HBM round-trip)
        __builtin_amdgcn_s_waitcnt(WAITCNT_LGKM0_ONLY);
        __builtin_amdgcn_s_barrier();
    }
    if (jw) {
        out[(size_t)BATCH * SEQ * HID + (size_t)b * HID + j] = hl;
        out[(size_t)BATCH * SEQ * HID + (size_t)BATCH * HID + (size_t)b * HID + j] = cs;
    }
}

extern "C" void kernel_launch(void* const* d_in, const int* in_sizes, int n_in,
                              void* d_out, int out_size, void* d_ws, size_t ws_size,
                              hipStream_t stream) {
    const float* x  = (const float*)d_in[0];
    const float* Ui = (const float*)d_in[1];
    const float* Vi = (const float*)d_in[2];
    const float* bi = (const float*)d_in[3];
    const float* Uf = (const float*)d_in[4];
    const float* Vf = (const float*)d_in[5];
    const float* bf = (const float*)d_in[6];
    const float* Uo = (const float*)d_in[7];
    const float* Vo = (const float*)d_in[8];
    const float* bo = (const float*)d_in[9];
    const float* Uc = (const float*)d_in[10];
    const float* Vc = (const float*)d_in[11];
    const float* bc = (const float*)d_in[12];

    f16* xU = (f16*)d_ws;   // [131072, 1024] fp16 = 256 MiB

    dim3 g1(1024, 8);   // (M/128, 4H/128)
    xu_gemm<<<g1, 256, 0, stream>>>(x, Ui, Uf, Uo, Uc, bi, bf, bo, bc, xU);
    lstm_rec<<<64, 512, 0, stream>>>(xU, Vi, Vf, Vo, Vc, (float*)d_out);
}

// Round 6
// 2132.027 us; speedup vs baseline: 1.2511x; 1.0033x over previous
//
#include <hip/hip_runtime.h>

#define BATCH 64
#define SEQ   2048
#define HID   256

typedef _Float16 f16;
typedef __attribute__((ext_vector_type(8))) _Float16 f16x8;
typedef __attribute__((ext_vector_type(4))) float f32x4;
typedef __attribute__((ext_vector_type(4))) int i32x4;

// s_waitcnt immediates (gfx9 encoding: vm[3:0]|exp[6:4]|lgkm[11:8]|vm_hi[15:14])
#define WAITCNT_LGKM0_ONLY 0xC07F   // lgkmcnt(0), vmcnt=63, expcnt=7
#define WAITCNT_VM12       0x0F7C   // vmcnt(12), lgkmcnt=15, expcnt=7

__device__ __forceinline__ float fast_sigmoid(float z) {
    return __builtin_amdgcn_rcpf(1.0f + __builtin_amdgcn_exp2f(-1.4426950408889634f * z));
}
__device__ __forceinline__ float fast_tanh(float z) {
    return 2.0f * __builtin_amdgcn_rcpf(1.0f + __builtin_amdgcn_exp2f(-2.8853900817779268f * z)) - 1.0f;
}

// async global->LDS, 16B per lane; LDS dest = uniform base + lane*16
typedef __attribute__((address_space(3))) unsigned int lds_u32;
typedef __attribute__((address_space(1))) const unsigned int gbl_u32;
__device__ __forceinline__ void gload16(void* l, const void* g) {
    __builtin_amdgcn_global_load_lds((gbl_u32*)g, (lds_u32*)l, 16, 0, 0);
}

// ---------------------------------------------------------------------------
// Phase 1: xU[m,0:1024] = x[m,0:256] @ [U_i|U_f|U_o|U_c] + bias -> fp16.
// (unchanged — verified)
// ---------------------------------------------------------------------------
__global__ __launch_bounds__(256, 2) void xu_gemm(
    const float* __restrict__ x,
    const float* __restrict__ U0, const float* __restrict__ U1,
    const float* __restrict__ U2, const float* __restrict__ U3,
    const float* __restrict__ b0, const float* __restrict__ b1,
    const float* __restrict__ b2, const float* __restrict__ b3,
    f16* __restrict__ xU)
{
    __shared__ f16 As[128][40];   // A[m][k], stride 80B (16B-aligned rows)
    __shared__ f16 Bs[128][40];   // B^T: Bs[n][k]

    const int m0 = blockIdx.x * 128;
    const int n0 = blockIdx.y * 128;
    const int gate = n0 >> 8;          // 128-col block lies within one gate
    const int nc0 = n0 & 255;
    const float* U    = (gate == 0) ? U0 : (gate == 1) ? U1 : (gate == 2) ? U2 : U3;
    const float* bias = (gate == 0) ? b0 : (gate == 1) ? b1 : (gate == 2) ? b2 : b3;

    const int tid  = threadIdx.x;
    const int wv   = tid >> 6;
    const int lane = tid & 63;
    const int arow = tid >> 1, acq = (tid & 1) * 16;   // A staging: 2 thr/row
    const int brow = tid >> 3, bcq = (tid & 7) * 16;   // B staging: 8 thr/k-row

    f32x4 acc[2][8];
#pragma unroll
    for (int mt = 0; mt < 2; ++mt)
#pragma unroll
        for (int nt = 0; nt < 8; ++nt) acc[mt][nt] = (f32x4){0.f, 0.f, 0.f, 0.f};

    for (int kc = 0; kc < 8; ++kc) {
        const int k0 = kc * 32;
        // stage A tile [128 x 32] fp32 -> fp16
        {
            const float* src = x + (size_t)(m0 + arow) * 256 + k0 + acq;
            float4 v0 = *(const float4*)src;
            float4 v1 = *(const float4*)(src + 4);
            float4 v2 = *(const float4*)(src + 8);
            float4 v3 = *(const float4*)(src + 12);
            f16x8 h0, h1;
            h0[0] = (f16)v0.x; h0[1] = (f16)v0.y; h0[2] = (f16)v0.z; h0[3] = (f16)v0.w;
            h0[4] = (f16)v1.x; h0[5] = (f16)v1.y; h0[6] = (f16)v1.z; h0[7] = (f16)v1.w;
            h1[0] = (f16)v2.x; h1[1] = (f16)v2.y; h1[2] = (f16)v2.z; h1[3] = (f16)v2.w;
            h1[4] = (f16)v3.x; h1[5] = (f16)v3.y; h1[6] = (f16)v3.z; h1[7] = (f16)v3.w;
            *(f16x8*)&As[arow][acq] = h0;
            *(f16x8*)&As[arow][acq + 8] = h1;
        }
        // stage B tile [32 x 128] transposed into Bs[n][k]
        {
            const float* src = U + (size_t)(k0 + brow) * 256 + nc0 + bcq;
            float4 v0 = *(const float4*)src;
            float4 v1 = *(const float4*)(src + 4);
            float4 v2 = *(const float4*)(src + 8);
            float4 v3 = *(const float4*)(src + 12);
            Bs[bcq +  0][brow] = (f16)v0.x;  Bs[bcq +  1][brow] = (f16)v0.y;
            Bs[bcq +  2][brow] = (f16)v0.z;  Bs[bcq +  3][brow] = (f16)v0.w;
            Bs[bcq +  4][brow] = (f16)v1.x;  Bs[bcq +  5][brow] = (f16)v1.y;
            Bs[bcq +  6][brow] = (f16)v1.z;  Bs[bcq +  7][brow] = (f16)v1.w;
            Bs[bcq +  8][brow] = (f16)v2.x;  Bs[bcq +  9][brow] = (f16)v2.y;
            Bs[bcq + 10][brow] = (f16)v2.z;  Bs[bcq + 11][brow] = (f16)v2.w;
            Bs[bcq + 12][brow] = (f16)v3.x;  Bs[bcq + 13][brow] = (f16)v3.y;
            Bs[bcq + 14][brow] = (f16)v3.z;  Bs[bcq + 15][brow] = (f16)v3.w;
        }
        __syncthreads();
        const int qk = (lane >> 4) * 8;
        f16x8 afrag0 = *(const f16x8*)&As[wv * 32 +  0 + (lane & 15)][qk];
        f16x8 afrag1 = *(const f16x8*)&As[wv * 32 + 16 + (lane & 15)][qk];
#pragma unroll
        for (int nt = 0; nt < 8; ++nt) {
            f16x8 bfrag = *(const f16x8*)&Bs[nt * 16 + (lane & 15)][qk];
            acc[0][nt] = __builtin_amdgcn_mfma_f32_16x16x32_f16(afrag0, bfrag, acc[0][nt], 0, 0, 0);
            acc[1][nt] = __builtin_amdgcn_mfma_f32_16x16x32_f16(afrag1, bfrag, acc[1][nt], 0, 0, 0);
        }
        __syncthreads();
    }
    // C/D: col = lane&15 (n), row = (lane>>4)*4 + reg (m)
    const int col = lane & 15, quad = lane >> 4;
#pragma unroll
    for (int nt = 0; nt < 8; ++nt) {
        const int n = n0 + nt * 16 + col;
        const float bv = bias[n & 255];
#pragma unroll
        for (int mt = 0; mt < 2; ++mt) {
#pragma unroll
            for (int r = 0; r < 4; ++r) {
                const int m = m0 + wv * 32 + mt * 16 + quad * 4 + r;
                xU[(size_t)m * 1024 + n] = (f16)(acc[mt][nt][r] + bv);
            }
        }
    }
}

// ---------------------------------------------------------------------------
// Phase 2: recurrence. 64 blocks x 1024 threads (16 waves, 4/SIMD).
// Round-6 restructure (math identical to r5):
//  - wave w owns cols [w*16, w*16+16); 16 MFMAs/wave (4 gates x 4 K-chunks),
//    breg halves to 64 regs -> fits 4 waves/SIMD for TLP overlap of the
//    matrix-pipe drain (r5 counters: MFMA 1036 cy + VALU 718 cy SERIAL).
//  - GATE-SPLIT ACT: the broadcast D-tile gives every lane all 4 gate sums;
//    lane (q,c) computes only gate q's activation for j = w*16+c
//    (sigmoid/tanh unified as A*rcp(1+exp2(B*z))+C, per-lane constants =
//    exact same formulas), then 3 shfl_xor gather {ig,fg,og,gg} into the
//    q==0 lane which owns cs/hv. ACT VALU per thread ~4x down,
//    transcendentals per j halve.
// ---------------------------------------------------------------------------
__global__ __launch_bounds__(1024, 1) void lstm_rec(
    const f16* __restrict__ xU,
    const float* __restrict__ V0, const float* __restrict__ V1,
    const float* __restrict__ V2, const float* __restrict__ V3,
    float* __restrict__ out)
{
    const int b    = blockIdx.x;
    const int tid  = threadIdx.x;
    const int wv   = tid >> 6;        // wave 0..15 -> cols [wv*16, wv*16+16)
    const int lane = tid & 63;
    const int q    = lane >> 4;       // k-slice group AND this lane's gate
    const int c    = lane & 15;       // column within the wave's 16-col tile
    const int j    = wv * 16 + c;     // this thread's hidden index
    const int jw   = (q == 0);        // writer lane for j

    // quantize V columns into B fragments: breg[g][kc] word u, byte bb =
    // V_g[kc*64 + q*16 + u*4 + bb][wv*16 + c], scale 2048 (identical to r5).
    // gate order g = 0:i, 1:f, 2:o, 3:c  (V2 = V_o, V3 = V_c)
    i32x4 breg[4][4];
#pragma unroll
    for (int g = 0; g < 4; ++g) {
        const float* vp = (g == 0) ? V0 : (g == 1) ? V1 : (g == 2) ? V2 : V3;
#pragma unroll
        for (int kc = 0; kc < 4; ++kc) {
#pragma unroll
            for (int u = 0; u < 4; ++u) {
                int packed = 0;
#pragma unroll
                for (int bb = 0; bb < 4; ++bb) {
                    const int k = kc * 64 + q * 16 + u * 4 + bb;
                    float v = vp[(size_t)k * 256 + j];
                    int qv = __float2int_rn(v * 2048.0f);
                    qv = qv > 127 ? 127 : (qv < -127 ? -127 : qv);
                    packed |= (qv & 0xFF) << (8 * bb);
                }
                breg[g][kc][u] = packed;
            }
        }
    }

    // per-lane activation constants: q<3 -> sigmoid, q==3 -> tanh
    const float actA = (q == 3) ? 2.0f : 1.0f;
    const float actB = (q == 3) ? -2.8853900817779268f : -1.4426950408889634f;
    const float actC = (q == 3) ? -1.0f : 0.0f;

    __shared__ alignas(16) int hq[2][64];          // packed int8 h, dbuf
    __shared__ alignas(16) f16 xq[8][1024];        // xU ring, 2KB/slot
    if (tid < 64) { hq[0][tid] = 0; hq[1][tid] = 0; }

    const f16* xrow = xU + (size_t)b * SEQ * 1024;
    float* hrow = out + (size_t)b * SEQ * HID;

    // prefill ring slots 0..6 (wave 0 issues; __syncthreads drains vmcnt)
    if (wv == 0) {
#pragma unroll
        for (int s = 0; s < 7; ++s) {
            const f16* src = xrow + (size_t)s * 1024 + lane * 8;
            gload16(&xq[s][0], src);
            gload16(&xq[s][512], src + 512);
        }
    }
    float cs = 0.0f, hl = 0.0f;
    __syncthreads();

    const float INVS = 1.0f / (127.0f * 2048.0f);

    for (int t = 0; t < SEQ; ++t) {
        const int cur = t & 1, nxt = cur ^ 1;
        // issue next ring slot (7 steps ahead); vmcnt(12) proves slot t+1 done
        if (wv == 0) {
            const int tf = (t + 7 < SEQ) ? (t + 7) : (SEQ - 1);
            const int sl7 = (t + 7) & 7;
            const f16* src = xrow + (size_t)tf * 1024 + lane * 8;
            gload16(&xq[sl7][0], src);
            gload16(&xq[sl7][512], src + 512);
            __builtin_amdgcn_s_waitcnt(WAITCNT_VM12);
        }

        // A fragments: broadcast b128 reads of packed-int8 h (4 K-chunks).
        // chunk kc, slice q -> int4 index kc*4 + q (same layout as r5).
        const int4* hp = (const int4*)&hq[cur][0];
        int4 h0 = hp[q];
        int4 h1 = hp[4 + q];
        int4 h2 = hp[8 + q];
        int4 h3 = hp[12 + q];
        const i32x4 a0 = (i32x4){h0.x, h0.y, h0.z, h0.w};
        const i32x4 a1 = (i32x4){h1.x, h1.y, h1.z, h1.w};
        const i32x4 a2 = (i32x4){h2.x, h2.y, h2.z, h2.w};
        const i32x4 a3 = (i32x4){h3.x, h3.y, h3.z, h3.w};

        // this lane's gate's xU term (gate slot = q): broadcast u16 read
        const int sl = t & 7;
        const float xz = (float)xq[sl][q * 256 + j];

        // --- MFMA phase: 4 depth-4 chains (one per gate), round-robin ---
        i32x4 acc[4];
#pragma unroll
        for (int g = 0; g < 4; ++g)
            acc[g] = __builtin_amdgcn_mfma_i32_16x16x64_i8(a0, breg[g][0], (i32x4){0,0,0,0}, 0, 0, 0);
#pragma unroll
        for (int g = 0; g < 4; ++g)
            acc[g] = __builtin_amdgcn_mfma_i32_16x16x64_i8(a1, breg[g][1], acc[g], 0, 0, 0);
#pragma unroll
        for (int g = 0; g < 4; ++g)
            acc[g] = __builtin_amdgcn_mfma_i32_16x16x64_i8(a2, breg[g][2], acc[g], 0, 0, 0);
#pragma unroll
        for (int g = 0; g < 4; ++g)
            acc[g] = __builtin_amdgcn_mfma_i32_16x16x64_i8(a3, breg[g][3], acc[g], 0, 0, 0);

        // --- gate-split ACT: lane (q,c) handles gate q of column j ---
        // static acc select (no runtime indexing -> no scratch)
        const int s  = (q == 0) ? acc[0][0]
                     : (q == 1) ? acc[1][0]
                     : (q == 2) ? acc[2][0] : acc[3][0];
        const float z = xz + (float)s * INVS;
        const float gval = actA * __builtin_amdgcn_rcpf(1.0f + __builtin_amdgcn_exp2f(actB * z)) + actC;
        // gather: e = gate q^1's value, v2 = gate q^2's e (= q^3's g), v3 = gate q^2's g
        const float e  = __shfl_xor(gval, 16, 64);   // q0:fg q1:ig q2:gg q3:og
        const float v2 = __shfl_xor(e,    32, 64);   // q0:gg q1:og q2:fg q3:ig
        const float v3 = __shfl_xor(gval, 32, 64);   // q0:og q1:gg q2:ig q3:fg
        // q==0 lane: gval=ig, e=fg, v2=gg, v3=og
        cs = e * cs + gval * v2;                     // fg*cs + ig*gg
        const float hv = v3 * fast_tanh(cs);         // og*tanh(cs)
        hl = hv;
        if (jw) {
            ((char*)&hq[nxt][0])[j] = (char)__float2int_rn(hv * 127.0f);
            hrow[t * HID + j] = hv;                  // fire-and-forget store
        }
        // barrier: drain LDS ops only (no vmcnt(0) HBM round-trip)
        __builtin_amdgcn_s_waitcnt(WAITCNT_LGKM0_ONLY);
        __builtin_amdgcn_s_barrier();
    }
    if (jw) {
        out[(size_t)BATCH * SEQ * HID + (size_t)b * HID + j] = hl;
        out[(size_t)BATCH * SEQ * HID + (size_t)BATCH * HID + (size_t)b * HID + j] = cs;
    }
}

extern "C" void kernel_launch(void* const* d_in, const int* in_sizes, int n_in,
                              void* d_out, int out_size, void* d_ws, size_t ws_size,
                              hipStream_t stream) {
    const float* x  = (const float*)d_in[0];
    const float* Ui = (const float*)d_in[1];
    const float* Vi = (const float*)d_in[2];
    const float* bi = (const float*)d_in[3];
    const float* Uf = (const float*)d_in[4];
    const float* Vf = (const float*)d_in[5];
    const float* bf = (const float*)d_in[6];
    const float* Uo = (const float*)d_in[7];
    const float* Vo = (const float*)d_in[8];
    const float* bo = (const float*)d_in[9];
    const float* Uc = (const float*)d_in[10];
    const float* Vc = (const float*)d_in[11];
    const float* bc = (const float*)d_in[12];

    f16* xU = (f16*)d_ws;   // [131072, 1024] fp16 = 256 MiB

    dim3 g1(1024, 8);   // (M/128, 4H/128)
    xu_gemm<<<g1, 256, 0, stream>>>(x, Ui, Uf, Uo, Uc, bi, bf, bo, bc, xU);
    lstm_rec<<<64, 1024, 0, stream>>>(xU, Vi, Vf, Vo, Vc, (float*)d_out);
}